// Round 1
// 172.829 us; speedup vs baseline: 1.0306x; 1.0306x over previous
//
#include <hip/hip_runtime.h>

using bf16 = __bf16;
typedef __bf16 bf16x8 __attribute__((ext_vector_type(8)));
typedef __bf16 bf16x4 __attribute__((ext_vector_type(4)));
typedef float  f32x4  __attribute__((ext_vector_type(4)));

#define MFMA16(a, b, c) __builtin_amdgcn_mfma_f32_16x16x32_bf16((a), (b), (c), 0, 0, 0)

static constexpr int S = 2048, E = 1024;
static constexpr float CSCALE = 0.18033688011112042f;  // 1/sqrt(64) * log2(e)

__device__ __forceinline__ void gld16(const bf16* g, bf16* l) {
    __builtin_amdgcn_global_load_lds((const __attribute__((address_space(1))) unsigned*)g,
                                     (__attribute__((address_space(3))) unsigned*)l, 16, 0, 0);
}

// ---------------- fused prep: cvt(hs) + transpose-cvt(w0) + transpose-cvt(w1) ----------------
__global__ __launch_bounds__(256) void k_prep(const float* __restrict__ hs, const float* __restrict__ w0,
                                              const float* __restrict__ w1, bf16* __restrict__ A0,
                                              bf16* __restrict__ Wt0, bf16* __restrict__ Wt1) {
    __shared__ float tile[32][33];
    const int bx = blockIdx.x;
    if (bx < 4096) {
        int i = (bx * 256 + threadIdx.x) * 4;
        float4 v = *(const float4*)(hs + i);
        bf16x4 o = { (bf16)v.x, (bf16)v.y, (bf16)v.z, (bf16)v.w };
        *(bf16x4*)(A0 + i) = o;
        return;
    }
    const float* in;
    bf16* outp;
    int K, N, nb, kb;
    if (bx < 4096 + 3072) {
        int j = bx - 4096; in = w0; outp = Wt0; K = 1024; N = 3072; nb = j % 96; kb = j / 96;
    } else {
        int j = bx - 7168; in = w1; outp = Wt1; K = 1024; N = 1024; nb = j % 32; kb = j / 32;
    }
    const int bxx = nb * 32, byy = kb * 32;
    const int tx = threadIdx.x & 31, ty = threadIdx.x >> 5;
#pragma unroll
    for (int i = 0; i < 32; i += 8)
        tile[ty + i][tx] = in[(long)(byy + ty + i) * N + bxx + tx];
    __syncthreads();
#pragma unroll
    for (int i = 0; i < 32; i += 8)
        outp[(long)(bxx + ty + i) * K + byy + tx] = (bf16)tile[tx][ty + i];
}

// ---------------- QKV GEMM: 256x256 tile, 8 waves (2Mx4N), BK=32, 4-slot LDS ring,
// phase-split schedule with counted vmcnt + setprio; Q row-major, K/V fragment-linear ----------------
__global__ __launch_bounds__(512, 2) void k_gemm_qkv(const bf16* __restrict__ A, const bf16* __restrict__ Bt,
                                                     const float* __restrict__ bias, bf16* __restrict__ Qs,
                                                     bf16* __restrict__ Kf, bf16* __restrict__ Vf, int Kk) {
    __shared__ __align__(16) char smem[131072];
    bf16* sA = (bf16*)smem;                // 4 slots x [256 rows][32 k] (chunk-swizzled)
    bf16* sB = (bf16*)(smem + 65536);      // 4 slots x [256 rows][32 k]

    const int NT = Kk >> 5;                // 32 K-tiles of BK=32

    // XCD-bijective swizzle (192 % 8 == 0): each XCD gets 24 consecutive tiles
    const int cpx = gridDim.x >> 3;
    const int bid = blockIdx.x;
    const int sid = (bid & 7) * cpx + (bid >> 3);
    const long bm = (long)(sid & 15) * 256;
    const int bnT = sid >> 4;              // 0..11
    const long bn = (long)bnT * 256;

    const int tid = threadIdx.x;
    const int w = tid >> 6, lane = tid & 63;
    const int col = lane & 15, quad = lane >> 4;
    const int wr = w >> 2, wc = w & 3;
    const int wrow = wr * 128, wcol = wc * 64;

    // staging source addresses: LDS chunk c holds global k-chunk (c&3)^((row>>1)&3)
    const int c0 = tid, c1 = 512 + tid;
    const int r0 = c0 >> 2, g0 = (c0 & 3) ^ ((r0 >> 1) & 3);
    const int r1 = c1 >> 2, g1 = (c1 & 3) ^ ((r1 >> 1) & 3);
    const bf16* gA0 = A + (bm + r0) * Kk + g0 * 8;
    const bf16* gA1 = A + (bm + r1) * Kk + g1 * 8;
    const bf16* gB0 = Bt + (bn + r0) * Kk + g0 * 8;
    const bf16* gB1 = Bt + (bn + r1) * Kk + g1 * 8;

    f32x4 acc[8][4] = {};

    // prologue: stage tiles 0,1,2 (12 vmem instrs); wait for tile 0 (8 = tiles 1,2 in flight)
#pragma unroll
    for (int tt = 0; tt < 3; ++tt) {
        bf16* dA = sA + tt * 8192;
        bf16* dB = sB + tt * 8192;
        gld16(gA0 + tt * 32, dA + w * 512);
        gld16(gA1 + tt * 32, dA + 4096 + w * 512);
        gld16(gB0 + tt * 32, dB + w * 512);
        gld16(gB1 + tt * 32, dB + 4096 + w * 512);
    }
    asm volatile("s_waitcnt vmcnt(8)" ::: "memory");
    __builtin_amdgcn_s_barrier();

#pragma unroll 1
    for (int t = 0; t < NT; ++t) {
        const bf16* sAs = sA + (t & 3) * 8192;
        const bf16* sBs = sB + (t & 3) * 8192;
        const int ts = t + 3;              // stage target: slot of tile t-1 (dead)
        bf16* dA = sA + (ts & 3) * 8192;
        bf16* dB = sB + (ts & 3) * 8192;

        // ---- phase 1: ds-load B(all) + A(low half); stage A(t+3); MFMA quadrant ----
        bf16x8 bfr[4], af[4];
#pragma unroll
        for (int nt = 0; nt < 4; ++nt) {
            const int row = wcol + nt * 16 + col;
            bfr[nt] = *(const bf16x8*)(sBs + row * 32 + ((quad ^ ((row >> 1) & 3)) * 8));
        }
#pragma unroll
        for (int mt = 0; mt < 4; ++mt) {
            const int row = wrow + mt * 16 + col;
            af[mt] = *(const bf16x8*)(sAs + row * 32 + ((quad ^ ((row >> 1) & 3)) * 8));
        }
        if (ts < NT) {
            gld16(gA0 + ts * 32, dA + w * 512);
            gld16(gA1 + ts * 32, dA + 4096 + w * 512);
        }
        __builtin_amdgcn_s_barrier();
        __builtin_amdgcn_s_setprio(1);
#pragma unroll
        for (int mt = 0; mt < 4; ++mt)
#pragma unroll
            for (int nt = 0; nt < 4; ++nt)
                acc[mt][nt] = MFMA16(af[mt], bfr[nt], acc[mt][nt]);
        __builtin_amdgcn_s_setprio(0);
        __builtin_amdgcn_s_barrier();

        // ---- phase 2: ds-load A(high half); stage B(t+3); MFMA quadrant; tile-boundary vmcnt ----
#pragma unroll
        for (int mt = 0; mt < 4; ++mt) {
            const int row = wrow + 64 + mt * 16 + col;
            af[mt] = *(const bf16x8*)(sAs + row * 32 + ((quad ^ ((row >> 1) & 3)) * 8));
        }
        if (ts < NT) {
            gld16(gB0 + ts * 32, dB + w * 512);
            gld16(gB1 + ts * 32, dB + 4096 + w * 512);
        }
        __builtin_amdgcn_s_barrier();
        __builtin_amdgcn_s_setprio(1);
#pragma unroll
        for (int mt = 0; mt < 4; ++mt)
#pragma unroll
            for (int nt = 0; nt < 4; ++nt)
                acc[4 + mt][nt] = MFMA16(af[mt], bfr[nt], acc[4 + mt][nt]);
        __builtin_amdgcn_s_setprio(0);
        // ensure tile t+1 fully landed before next group's ds_reads; keep t+2,t+3 in flight
        if (t < NT - 3)       asm volatile("s_waitcnt vmcnt(8)" ::: "memory");
        else if (t == NT - 3) asm volatile("s_waitcnt vmcnt(4)" ::: "memory");
        else if (t == NT - 2) asm volatile("s_waitcnt vmcnt(0)" ::: "memory");
        __builtin_amdgcn_s_barrier();
    }

    // ---------------- epilogue (per-wave private; no cross-wave barriers) ----------------
    const int seg = bnT >> 2;              // 0: Q, 1: K, 2: V (256 cols stay within one segment)

    if (seg == 0) {
#pragma unroll
        for (int nt = 0; nt < 4; ++nt) {
            const long gc = bn + wcol + nt * 16 + col;
            const float bv = bias[gc];
#pragma unroll
            for (int mt = 0; mt < 8; ++mt) {
                const long gr = bm + wrow + mt * 16 + quad * 4;
#pragma unroll
                for (int r = 0; r < 4; ++r)
                    Qs[(gr + r) * 1024 + gc] = (bf16)((acc[mt][nt][r] + bv) * CSCALE);
            }
        }
        return;
    }

    bf16* myT = (bf16*)smem + w * (64 * 72);   // per-wave 64x72 bf16 scratch (9 KiB)
    const int bmi = (int)bm;
    const int b = bmi >> 11;
    const int ktw = ((bmi & 2047) >> 6) + wr * 2;   // wave's first 64-row K-tile index
    float bv[4];
#pragma unroll
    for (int nt = 0; nt < 4; ++nt) bv[nt] = bias[bn + wcol + nt * 16 + col];

    if (seg == 1) {
        const int head = (((int)bn - 1024) >> 6) + wc;
        const int bh = b * 16 + head;
#pragma unroll
        for (int p = 0; p < 2; ++p) {
            // write 64 seq rows x 64 d cols (row-major, seq-major)
#pragma unroll
            for (int mt2 = 0; mt2 < 4; ++mt2)
#pragma unroll
                for (int nt = 0; nt < 4; ++nt)
#pragma unroll
                    for (int r = 0; r < 4; ++r)
                        myT[(mt2 * 16 + quad * 4 + r) * 72 + nt * 16 + col] =
                            (bf16)(acc[p * 4 + mt2][nt][r] + bv[nt]);
            // read MFMA A-fragments: K[kt*64 + mtp*16 + col][half*32 + quad*8 .. +8]
#pragma unroll
            for (int mtp = 0; mtp < 4; ++mtp)
#pragma unroll
                for (int half = 0; half < 2; ++half) {
                    bf16x8 ch = *(const bf16x8*)(myT + (mtp * 16 + col) * 72 + half * 32 + quad * 8);
                    const long chunk = ((long)(bh * 32 + ktw + p) * 8 + mtp * 2 + half) * 64 + lane;
                    *(bf16x8*)(Kf + chunk * 8) = ch;
                }
        }
    } else {
        const int head = (((int)bn - 2048) >> 6) + wc;
        const int bh = b * 16 + head;
#pragma unroll
        for (int p = 0; p < 2; ++p) {
            // write V^T: [d][seq-local] col-major, vectorized along seq
#pragma unroll
            for (int nt = 0; nt < 4; ++nt)
#pragma unroll
                for (int mt2 = 0; mt2 < 4; ++mt2) {
                    bf16x4 pk = { (bf16)(acc[p * 4 + mt2][nt][0] + bv[nt]),
                                  (bf16)(acc[p * 4 + mt2][nt][1] + bv[nt]),
                                  (bf16)(acc[p * 4 + mt2][nt][2] + bv[nt]),
                                  (bf16)(acc[p * 4 + mt2][nt][3] + bv[nt]) };
                    *(bf16x4*)(myT + (nt * 16 + col) * 72 + mt2 * 16 + quad * 4) = pk;
                }
            // read MFMA A-fragments: V^T[dt*16 + col][ks*32 + quad*8 .. +8]
#pragma unroll
            for (int dt = 0; dt < 4; ++dt)
#pragma unroll
                for (int ks = 0; ks < 2; ++ks) {
                    bf16x8 ch = *(const bf16x8*)(myT + (dt * 16 + col) * 72 + ks * 32 + quad * 8);
                    const long chunk = ((long)(bh * 32 + ktw + p) * 8 + dt * 2 + ks) * 64 + lane;
                    *(bf16x8*)(Vf + chunk * 8) = ch;
                }
        }
    }
}

// ---------------- bf16 GEMM 64x128 tile, BK=64, XOR-swizzled (proj) ----------------
__global__ __launch_bounds__(256) void k_gemm_bt64(const bf16* __restrict__ A, const bf16* __restrict__ Bt,
                                                    const float* __restrict__ bias, float* __restrict__ Cout,
                                                    int Mm, int Nn, int Kk) {
    const int bm = blockIdx.x * 64;
    const int bn = blockIdx.y * 128;
    const int tid = threadIdx.x;
    const int w = tid >> 6, lane = tid & 63;
    const int wm = (w >> 1) * 32, wn = (w & 1) * 64;
    const int col = lane & 15, quad = lane >> 4;

    __shared__ bf16 sA[64 * 64];
    __shared__ bf16 sB[128 * 64];

    const bf16* pA[2]; bf16* lA[2];
#pragma unroll
    for (int i = 0; i < 2; i++) {
        const int c = i * 256 + w * 64 + lane;
        const int r = c >> 3, sl = (c & 7) ^ (r & 7);
        pA[i] = A + (long)(bm + r) * Kk + sl * 8;
        lA[i] = sA + i * 2048 + w * 512;
    }
    const bf16* pB[4]; bf16* lB[4];
#pragma unroll
    for (int i = 0; i < 4; i++) {
        const int c = i * 256 + w * 64 + lane;
        const int r = c >> 3, sl = (c & 7) ^ (r & 7);
        pB[i] = Bt + (long)(bn + r) * Kk + sl * 8;
        lB[i] = sB + i * 2048 + w * 512;
    }

    f32x4 acc[2][4] = {};

    for (int k0 = 0; k0 < Kk; k0 += 64) {
        __syncthreads();
#pragma unroll
        for (int i = 0; i < 2; i++) gld16(pA[i] + k0, lA[i]);
#pragma unroll
        for (int i = 0; i < 4; i++) gld16(pB[i] + k0, lB[i]);
        __syncthreads();
#pragma unroll
        for (int h = 0; h < 2; h++) {
            bf16x8 af[2], bfr[4];
#pragma unroll
            for (int mt = 0; mt < 2; mt++) {
                const int row = wm + mt * 16 + col;
                af[mt] = *(const bf16x8*)(sA + row * 64 + (((h * 4 + quad) ^ (col & 7)) * 8));
            }
#pragma unroll
            for (int nt = 0; nt < 4; nt++) {
                const int row = wn + nt * 16 + col;
                bfr[nt] = *(const bf16x8*)(sB + row * 64 + (((h * 4 + quad) ^ (col & 7)) * 8));
            }
#pragma unroll
            for (int mt = 0; mt < 2; mt++)
#pragma unroll
                for (int nt = 0; nt < 4; nt++)
                    acc[mt][nt] = MFMA16(af[mt], bfr[nt], acc[mt][nt]);
        }
    }

#pragma unroll
    for (int mt = 0; mt < 2; mt++) {
        const int gr = bm + wm + mt * 16 + quad * 4;
#pragma unroll
        for (int nt = 0; nt < 4; nt++) {
            const int gc = bn + wn + nt * 16 + col;
            const float bv = bias[gc];
#pragma unroll
            for (int r = 0; r < 4; r++)
                Cout[(long)(gr + r) * Nn + gc] = acc[mt][nt][r] + bv;
        }
    }
}

// ---------------- causal flash attention: kt-split uniform waves + flash-decode merge ----------------
__global__ __launch_bounds__(128) void k_attn(const bf16* __restrict__ Qs, const bf16* __restrict__ Kf,
                                              const bf16* __restrict__ Vf, bf16* __restrict__ out) {
    const int bh = blockIdx.x & 31;
    const int tp = blockIdx.x >> 5;           // tile pair 0..31
    const int b = bh >> 4, h = bh & 15;
    const int tid = threadIdx.x;
    const int w = tid >> 6, lane = tid & 63;
    const int col = lane & 15, quad = lane >> 4;

    __shared__ bf16 sP[2][32 * 72];
    __shared__ float M[2][64][36];            // [sel][lane][0..31 O | 32 m0 33 l0 34 m1 35 l1]
    bf16* pw = sP[w];

    const bf16* kfb = Kf + ((long)bh << 17) + lane * 8;
    const bf16* vfb = Vf + ((long)bh << 17) + lane * 8;

#pragma unroll 1
    for (int sel = 0; sel < 2; sel++) {
        const int t = sel ? 63 - tp : tp;
        const int q0 = t * 32;
        const int nkt = (t >> 1) + 1;
        const int kA = nkt >> 1;
        const int kbeg = w ? kA : 0;
        const int kend = w ? nkt : kA;

        bf16x8 bq[2][2];
#pragma unroll
        for (int qg = 0; qg < 2; qg++) {
            const bf16* qp = Qs + (long)(b * S + q0 + qg * 16 + col) * E + h * 64 + quad * 8;
            bq[qg][0] = *(const bf16x8*)(qp);
            bq[qg][1] = *(const bf16x8*)(qp + 32);
        }
        float m_[2] = { -1e30f, -1e30f }, l_[2] = { 0.f, 0.f };
        f32x4 o[2][4] = {};

#pragma unroll 1
        for (int kt = kbeg; kt < kend; kt++) {
            bf16x8 kfr[4][2], vfr[4][2];
#pragma unroll
            for (int mt = 0; mt < 4; mt++)
#pragma unroll
                for (int half = 0; half < 2; half++)
                    kfr[mt][half] = *(const bf16x8*)(kfb + ((long)(kt * 8 + mt * 2 + half) << 9));
#pragma unroll
            for (int dt = 0; dt < 4; dt++)
#pragma unroll
                for (int ks = 0; ks < 2; ks++)
                    vfr[dt][ks] = *(const bf16x8*)(vfb + ((long)(kt * 8 + dt * 2 + ks) << 9));

            f32x4 s[2][4];
#pragma unroll
            for (int mt = 0; mt < 4; mt++)
#pragma unroll
                for (int qg = 0; qg < 2; qg++) {
                    f32x4 z = {};
                    z = MFMA16(kfr[mt][0], bq[qg][0], z);
                    z = MFMA16(kfr[mt][1], bq[qg][1], z);
                    s[qg][mt] = z;
                }
            if (kt == nkt - 1) {  // diagonal tile (always in wave 1's range)
#pragma unroll
                for (int qg = 0; qg < 2; qg++) {
                    const int qrow = q0 + qg * 16 + col;
#pragma unroll
                    for (int mt = 0; mt < 4; mt++)
#pragma unroll
                        for (int r = 0; r < 4; r++)
                            if (kt * 64 + mt * 16 + quad * 4 + r > qrow) s[qg][mt][r] = -1e30f;
                }
            }
#pragma unroll
            for (int qg = 0; qg < 2; qg++) {
                float cm = -1e30f;
#pragma unroll
                for (int mt = 0; mt < 4; mt++)
#pragma unroll
                    for (int r = 0; r < 4; r++) cm = fmaxf(cm, s[qg][mt][r]);
                cm = fmaxf(cm, __shfl_xor(cm, 16));
                cm = fmaxf(cm, __shfl_xor(cm, 32));
                const float mnew = fmaxf(m_[qg], cm);
                const float alpha = __builtin_amdgcn_exp2f(m_[qg] - mnew);
                m_[qg] = mnew;
                float rs = 0.f;
#pragma unroll
                for (int mt = 0; mt < 4; mt++)
#pragma unroll
                    for (int r = 0; r < 4; r++) {
                        float pe = __builtin_amdgcn_exp2f(s[qg][mt][r] - mnew);
                        s[qg][mt][r] = pe;
                        rs += pe;
                    }
                l_[qg] = l_[qg] * alpha + rs;
#pragma unroll
                for (int dt = 0; dt < 4; dt++)
#pragma unroll
                    for (int r = 0; r < 4; r++) o[qg][dt][r] *= alpha;
#pragma unroll
                for (int mt = 0; mt < 4; mt++) {
                    bf16x4 pk = { (bf16)s[qg][mt][0], (bf16)s[qg][mt][1],
                                  (bf16)s[qg][mt][2], (bf16)s[qg][mt][3] };
                    *(bf16x4*)(pw + (qg * 16 + col) * 72 + mt * 16 + quad * 4) = pk;
                }
            }
#pragma unroll
            for (int ks = 0; ks < 2; ks++) {
                bf16x8 ap[2];
#pragma unroll
                for (int qg = 0; qg < 2; qg++)
                    ap[qg] = *(const bf16x8*)(pw + (qg * 16 + col) * 72 + ks * 32 + quad * 8);
#pragma unroll
                for (int dt = 0; dt < 4; dt++)
#pragma unroll
                    for (int qg = 0; qg < 2; qg++)
                        o[qg][dt] = MFMA16(vfr[dt][ks], ap[qg], o[qg][dt]);
            }
        }

        // finish per-lane l reduction -> replicated row sums
#pragma unroll
        for (int qg = 0; qg < 2; qg++) {
            float lt = l_[qg];
            lt += __shfl_xor(lt, 16);
            lt += __shfl_xor(lt, 32);
            l_[qg] = lt;
        }

        if (w == 0) {  // publish lower-half partials
#pragma unroll
            for (int qg = 0; qg < 2; qg++) {
#pragma unroll
                for (int dt = 0; dt < 4; dt++)
                    *(f32x4*)&M[sel][lane][qg * 16 + dt * 4] = o[qg][dt];
                M[sel][lane][32 + qg * 2] = m_[qg];
                M[sel][lane][33 + qg * 2] = l_[qg];
            }
        }
        __syncthreads();
        if (w == 1) {  // merge + output
#pragma unroll
            for (int qg = 0; qg < 2; qg++) {
                const float m0 = M[sel][lane][32 + qg * 2];
                const float l0 = M[sel][lane][33 + qg * 2];
                const float mm = fmaxf(m0, m_[qg]);
                const float a0 = __builtin_amdgcn_exp2f(m0 - mm);
                const float a1 = __builtin_amdgcn_exp2f(m_[qg] - mm);
                const float li = 1.f / (l0 * a0 + l_[qg] * a1);
                bf16* op = out + (long)(b * S + q0 + qg * 16 + col) * E + h * 64 + quad * 4;
#pragma unroll
                for (int dt = 0; dt < 4; dt++) {
                    f32x4 o0 = *(const f32x4*)&M[sel][lane][qg * 16 + dt * 4];
                    bf16x4 ov;
#pragma unroll
                    for (int r = 0; r < 4; r++)
                        ov[r] = (bf16)((o0[r] * a0 + o[qg][dt][r] * a1) * li);
                    *(bf16x4*)(op + dt * 16) = ov;
                }
            }
        }
    }
}

extern "C" void kernel_launch(void* const* d_in, const int* in_sizes, int n_in,
                              void* d_out, int out_size, void* d_ws, size_t ws_size,
                              hipStream_t stream) {
    const float* hs = (const float*)d_in[0];   // [2,2048,1024]
    const float* w0 = (const float*)d_in[1];   // [1024,3072]
    const float* b0 = (const float*)d_in[2];   // [3072]
    const float* w1 = (const float*)d_in[3];   // [1024,1024]
    const float* b1 = (const float*)d_in[4];   // [1024]
    float* outp = (float*)d_out;               // [2,2048,1024] fp32

    char* ws = (char*)d_ws;
    bf16* A0    = (bf16*)(ws);                   // 8 MB
    bf16* Wt0   = (bf16*)(ws + 8388608);         // 6 MB
    bf16* Wt1   = (bf16*)(ws + 14680064);        // 2 MB
    bf16* Qs    = (bf16*)(ws + 16777216);        // 8 MB  [4096][1024] scaled Q
    bf16* Kf    = (bf16*)(ws + 25165824);        // 8 MB  fragment-linear K
    bf16* Vf    = (bf16*)(ws + 33554432);        // 8 MB  fragment-linear V^T
    bf16* attnO = (bf16*)(ws + 41943040);        // 8 MB

    k_prep<<<8192, 256, 0, stream>>>(hs, w0, w1, A0, Wt0, Wt1);
    k_gemm_qkv<<<192, 512, 0, stream>>>(A0, Wt0, b0, Qs, Kf, Vf, 1024);
    k_attn<<<1024, 128, 0, stream>>>(Qs, Kf, Vf, attnO);
    k_gemm_bt64<<<dim3(64, 8), 256, 0, stream>>>(attnO, Wt1, b1, outp, 4096, 1024, 1024);
}